// Round 7
// baseline (195.349 us; speedup 1.0000x reference)
//
#include <hip/hip_runtime.h>
#include <hip/hip_bf16.h>
#include <stdint.h>

// Problem constants
#define BATCH 4
#define SEQ   1024
#define EMB   1024
#define NHEAD 16
#define HDIM  64
#define MTOT  (BATCH*SEQ)          // 4096 rows
#define MELEM (MTOT*EMB)           // 4,194,304 elements per [B,S,E] tensor

typedef __attribute__((ext_vector_type(8))) short short8;
typedef __attribute__((ext_vector_type(4))) float f32x4;
typedef __attribute__((ext_vector_type(16))) float f32x16;
typedef __attribute__((ext_vector_type(4))) unsigned short us4;
typedef __attribute__((ext_vector_type(2))) unsigned int u32x2;
typedef __attribute__((ext_vector_type(4))) unsigned int u32x4;

// counted vmem wait (T4): NEVER drain to 0 inside a pipelined loop.
#define WAITV(N) asm volatile("s_waitcnt vmcnt(" #N ")" ::: "memory")
#define BARRIER() __builtin_amdgcn_s_barrier()

// fast f32->bf16: round-half-up via integer add (inputs finite, no NaN).
static __device__ __forceinline__ unsigned short f2bf_fast(float f) {
  unsigned u = __builtin_bit_cast(unsigned, f);
  return (unsigned short)((u + 0x8000u) >> 16);
}

// packed f32x2 -> bf16x2 (RNE), no builtin on gfx950 (T12/m240) -> inline asm
static __device__ __forceinline__ unsigned cvt_pk_bf16(float lo, float hi) {
  unsigned r;
  asm("v_cvt_pk_bf16_f32 %0, %1, %2" : "=v"(r) : "v"(lo), "v"(hi));
  return r;
}

// async global->LDS, 16B per lane. lds ptr must be WAVE-UNIFORM base;
// HW scatters lane i to base + i*16. (m97 recipe)
static __device__ __forceinline__ void cp16(const void* g, const void* lds_uniform) {
  __builtin_amdgcn_global_load_lds(
      (const __attribute__((address_space(1))) unsigned int*)(uintptr_t)g,
      (__attribute__((address_space(3))) unsigned int*)(unsigned int)(uintptr_t)lds_uniform,
      16, 0, 0);
}

// ---------------------------------------------------------------- prep: cvt f32->bf16 (Re,Im) + W transpose x4
// bid 0..4095: Re cvt | 4096..8191: Im cvt | 8192..12287: wtrans (z = (bid-8192)>>10)
__global__ __launch_bounds__(256) void prep(const float* __restrict__ Re,
                                            const float* __restrict__ Im,
                                            short* __restrict__ Rebf,
                                            short* __restrict__ Imbf,
                                            const float* __restrict__ W0,
                                            const float* __restrict__ W1,
                                            const float* __restrict__ W2,
                                            const float* __restrict__ W3,
                                            short* __restrict__ WtBase) {
  __shared__ short tile[32][33];
  const int bid = blockIdx.x;
  if (bid < 8192) {
    const float* in  = (bid >= 4096) ? Im   : Re;
    short*       out = (bid >= 4096) ? Imbf : Rebf;
    int i = (bid & 4095) * 256 + threadIdx.x;   // each thread: 4 elements
    float4 f = ((const float4*)in)[i];
    unsigned r0 = ((unsigned)f2bf_fast(f.y) << 16) | f2bf_fast(f.x);
    unsigned r1 = ((unsigned)f2bf_fast(f.w) << 16) | f2bf_fast(f.z);
    ((uint2*)out)[i] = make_uint2(r0, r1);
  } else {
    const int wb = bid - 8192;
    const int z = wb >> 10;
    const float* W = (z == 0) ? W0 : (z == 1) ? W1 : (z == 2) ? W2 : W3;
    short* Wt = WtBase + (size_t)z * EMB * EMB;
    const int rem = wb & 1023;
    const int nT = (rem & 31) * 32, kT = (rem >> 5) * 32;
    const int tx = threadIdx.x & 31, ty = threadIdx.x >> 5;   // 32 x 8
    #pragma unroll
    for (int i = 0; i < 4; ++i)
      tile[ty + 8*i][tx] = (short)f2bf_fast(W[(size_t)(kT + ty + 8*i) * EMB + nT + tx]);
    __syncthreads();
    #pragma unroll
    for (int i = 0; i < 4; ++i)
      Wt[(size_t)(nT + ty + 8*i) * EMB + kT + tx] = tile[tx][ty + 8*i];
  }
}

// ---------------------------------------------------------------- fused QKV GEMM, 128x128 tiles + T4 pipeline
// N fused to 3072. grid (24,32) = 768 blocks, 64 KB LDS -> 2 blocks/CU. (control — parked at ~41 us;
// three structurally different variants all land 40-42.5: short-K regime is the invariant.)
__global__ __launch_bounds__(256) void gemm_qkv(const short* __restrict__ A,
                                                const short* __restrict__ Wt,
                                                const float* __restrict__ bq,
                                                const float* __restrict__ bk,
                                                const float* __restrict__ bv,
                                                const float* __restrict__ pos,
                                                short* __restrict__ QKbase,
                                                short* __restrict__ vtOut) {
  const int m0 = blockIdx.y * 128, n0 = blockIdx.x * 128;
  const int z = n0 >> 10;                       // 0=Q 1=K 2=V (1024 % 128 == 0)
  const float* bias = (z == 0) ? bq : (z == 1 ? bk : bv);

  __shared__ __align__(16) short As[2][128 * 64];  // 2 x 16 KB
  __shared__ __align__(16) short Bs[2][128 * 64];  // 2 x 16 KB

  const int t = threadIdx.x;
  const int lane = t & 63, w = t >> 6;
  const int wm = w >> 1, wn = w & 1;            // wave tile 64m x 64n
  const int quad = lane >> 4, l16 = lane & 15;
  const int lrow8 = lane >> 3, lchunk = lane & 7;
  const int gch = lchunk ^ lrow8;               // swizzled source chunk
  const int sw7 = l16 & 7;

  const short* Arow = A  + (size_t)(m0 + w * 32 + lrow8) * EMB + gch * 8;
  const short* Brow = Wt + (size_t)(n0 + w * 32 + lrow8) * EMB + gch * 8;

  f32x4 acc[4][4] = {};

  auto STAGE = [&](short* as, short* bs, int k0) {   // 8 cp16 per thread
    #pragma unroll
    for (int s = 0; s < 4; ++s)
      cp16(Arow + (size_t)(s * 8) * EMB + k0, &as[(w * 32 + s * 8) * 64]);
    #pragma unroll
    for (int s = 0; s < 4; ++s)
      cp16(Brow + (size_t)(s * 8) * EMB + k0, &bs[(w * 32 + s * 8) * 64]);
  };
  auto COMPUTE = [&](const short* as, const short* bs) {
    #pragma unroll
    for (int ks = 0; ks < 2; ++ks) {
      const int chv = ((ks << 2) + quad) ^ sw7;
      short8 af[4], bfr[4];
      #pragma unroll
      for (int i = 0; i < 4; ++i)
        af[i] = *(const short8*)&as[(wm * 64 + i * 16 + l16) * 64 + chv * 8];
      #pragma unroll
      for (int j = 0; j < 4; ++j)
        bfr[j] = *(const short8*)&bs[(wn * 64 + j * 16 + l16) * 64 + chv * 8];
      #pragma unroll
      for (int i = 0; i < 4; ++i)
        #pragma unroll
        for (int j = 0; j < 4; ++j)
          acc[i][j] = __builtin_amdgcn_mfma_f32_16x16x32_bf16(af[i], bfr[j], acc[i][j], 0, 0, 0);
    }
  };

  STAGE(As[0], Bs[0], 0);      // tile 0 in flight
  STAGE(As[1], Bs[1], 64);     // tile 1 in flight (16 loads outstanding)

  #pragma unroll 1
  for (int p = 0; p < 7; ++p) {
    WAITV(8); BARRIER();                    // own tile-(2p) loads done; all waves synced
    COMPUTE(As[0], Bs[0]);                  // k = p*128
    BARRIER();                              // all waves done reading buf0
    STAGE(As[0], Bs[0], p * 128 + 128);     // tile 2p+2
    WAITV(8); BARRIER();
    COMPUTE(As[1], Bs[1]);                  // k = p*128 + 64
    BARRIER();
    STAGE(As[1], Bs[1], p * 128 + 192);     // tile 2p+3
  }
  WAITV(8); BARRIER();
  COMPUTE(As[0], Bs[0]);                    // k = 896
  BARRIER();
  WAITV(0); BARRIER();
  COMPUTE(As[1], Bs[1]);                    // k = 960

  // epilogue: C row = quad*4+r, col = l16
  #pragma unroll
  for (int i = 0; i < 4; ++i) {
    int mbase = m0 + wm * 64 + i * 16 + quad * 4;
    #pragma unroll
    for (int j = 0; j < 4; ++j) {
      int n = n0 + wn * 64 + j * 16 + l16;
      int nl = n & 1023;
      float bn = bias[nl];
      int d = nl & (HDIM - 1);
      if (z == 2) {
        // write V transposed: [b,h,d,s] so attn stages Vt rows contiguously
        int bh = (mbase >> 10) * NHEAD + (nl >> 6);
        int s = mbase & (SEQ - 1);
        us4 pk;
        #pragma unroll
        for (int r = 0; r < 4; ++r) {
          float v = acc[i][j][r] + bn + pos[(size_t)(mbase + r) * HDIM + d];
          pk[r] = f2bf_fast(v);
        }
        *(us4*)&vtOut[((size_t)bh * HDIM + d) * SEQ + s] = pk;
      } else {
        #pragma unroll
        for (int r = 0; r < 4; ++r) {
          int mm = mbase + r;
          float v = acc[i][j][r] + bn + pos[(size_t)mm * HDIM + d];
          QKbase[(size_t)z * MELEM + (size_t)mm * EMB + nl] = (short)f2bf_fast(v);
        }
      }
    }
  }
}

// ---------------------------------------------------------------- Wo GEMM: 64x64 tiles, true pipeline (control)
__global__ __launch_bounds__(256) void gemm_wo(const short* __restrict__ A,
                                               const short* __restrict__ Bt,
                                               const float* __restrict__ bias,
                                               float* __restrict__ out) {
  const int m0 = blockIdx.y * 64, n0 = blockIdx.x * 64;

  __shared__ __align__(16) short As[2][64 * 64];
  __shared__ __align__(16) short Bs[2][64 * 64];

  const int t = threadIdx.x;
  const int lane = t & 63, w = t >> 6;
  const int wm = w >> 1, wn = w & 1;          // wave tile: 32m x 32n
  const int quad = lane >> 4, l16 = lane & 15;
  const int lrow8 = lane >> 3, lchunk = lane & 7;
  const int gch = lchunk ^ lrow8;
  const int sw7 = l16 & 7;

  const short* Arow = A  + (size_t)(m0 + w * 16 + lrow8) * EMB + gch * 8;
  const short* Brow = Bt + (size_t)(n0 + w * 16 + lrow8) * EMB + gch * 8;

  f32x4 acc[2][2] = {};

  auto STAGE = [&](short* as, short* bs, int k0) {   // 4 cp16 per thread
    #pragma unroll
    for (int s = 0; s < 2; ++s) {
      cp16(Arow + (size_t)(s * 8) * EMB + k0, &as[(w * 16 + s * 8) * 64]);
      cp16(Brow + (size_t)(s * 8) * EMB + k0, &bs[(w * 16 + s * 8) * 64]);
    }
  };
  auto COMPUTE = [&](const short* as, const short* bs) {
    #pragma unroll
    for (int ks = 0; ks < 2; ++ks) {
      const int chv = ((ks << 2) + quad) ^ sw7;
      short8 af[2], bfr[2];
      #pragma unroll
      for (int i = 0; i < 2; ++i)
        af[i] = *(const short8*)&as[(wm * 32 + i * 16 + l16) * 64 + chv * 8];
      #pragma unroll
      for (int j = 0; j < 2; ++j)
        bfr[j] = *(const short8*)&bs[(wn * 32 + j * 16 + l16) * 64 + chv * 8];
      #pragma unroll
      for (int i = 0; i < 2; ++i)
        #pragma unroll
        for (int j = 0; j < 2; ++j)
          acc[i][j] = __builtin_amdgcn_mfma_f32_16x16x32_bf16(af[i], bfr[j], acc[i][j], 0, 0, 0);
    }
  };

  STAGE(As[0], Bs[0], 0);
  STAGE(As[1], Bs[1], 64);

  #pragma unroll 1
  for (int p = 0; p < 7; ++p) {
    WAITV(4); BARRIER();
    COMPUTE(As[0], Bs[0]);
    BARRIER();
    STAGE(As[0], Bs[0], p * 128 + 128);
    WAITV(4); BARRIER();
    COMPUTE(As[1], Bs[1]);
    BARRIER();
    STAGE(As[1], Bs[1], p * 128 + 192);
  }
  WAITV(4); BARRIER();
  COMPUTE(As[0], Bs[0]);
  BARRIER();
  WAITV(0); BARRIER();
  COMPUTE(As[1], Bs[1]);

  #pragma unroll
  for (int i = 0; i < 2; ++i) {
    int mbase = m0 + wm * 32 + i * 16 + quad * 4;
    #pragma unroll
    for (int j = 0; j < 2; ++j) {
      int n = n0 + wn * 32 + j * 16 + l16;
      float bn = bias[n];
      #pragma unroll
      for (int r = 0; r < 4; ++r)
        out[(size_t)(mbase + r) * EMB + n] = acc[i][j][r] + bn;
    }
  }
}

// ---------------------------------------------------------------- flash attention v4: 32x32 MFMA,
// swapped QK^T + in-register P (T12), and NOW double-buffered tiles with counted vmcnt (T4).
// R7: the single-buffered v3 committed staging via __syncthreads drains with issue->wait
// distances of only one phase (Vt: one QK phase; K/Im: exp+PV) — several hundred cycles of
// exposed HBM latency per iteration at 2 (grid-limited) blocks/CU. v4 double-buffers the
// whole K|Im|Vt set (2 x 24 KB): set(kt+2) is issued after the post-compute barrier and
// waited TWO full compute phases later via WAITV(6) (own 6 oldest = current set; next set
// stays in flight). Compute is one contiguous QK+exp+PV region; T5 setprio wraps the MFMA
// clusters (proven +4-7% on attn, m191). Last iteration peeled with WAITV(0).
__global__ __launch_bounds__(256) void attn(const short* __restrict__ Qp,
                                            const short* __restrict__ Kp,
                                            const short* __restrict__ VtG,
                                            const short* __restrict__ Imb,
                                            short* __restrict__ attnA) {
  const int qb = blockIdx.y * 128;
  const int bh = blockIdx.x;
  const int b = bh >> 4, h = bh & 15;
  const int t = threadIdx.x, lane = t & 63, w = t >> 6;   // w: 0..3
  const int c31 = lane & 31;       // q-row (QK out col / PV A row) and d-row (PV out col)
  const int hi  = lane >> 5;       // half-wave: k-slice selector
  const int lrow8 = lane >> 3, lchunk = lane & 7;
  const int gch = lchunk ^ lrow8;  // staging swizzle: LDS[row][ch] = G[row][ch ^ (row&7)]

  __shared__ __align__(16) short tiles[2][3 * 64 * 64];   // dbuf x (K | Im | Vt), 49152 B

  // Q/Im B-fragments in regs: lane holds row (qb + w*32 + c31), k = ks*16 + hi*8 .. +8
  const int qrow = qb + w * 32 + c31;
  const size_t qbase = ((size_t)(b * SEQ + qrow)) * EMB + h * HDIM + hi * 8;
  short8 bq_[4], bim[4];
  #pragma unroll
  for (int ks = 0; ks < 4; ++ks) {
    bq_[ks] = *(const short8*)&Qp [qbase + ks * 16];
    bim[ks] = *(const short8*)&Imb[qbase + ks * 16];
  }

  float lrA = 0.f, lrB = 0.f;      // per-lane softmax denominator (q = qrow), split chains
  f32x16 o0 = {}, o1 = {};         // PV accum, d-blocks 0/1

  const float SC = 0.03125f * 1.44269504089f;   // /sqrt(1024) * log2(e)
  const size_t kimBase = ((size_t)b * SEQ) * EMB + h * HDIM + gch * 8;
  const size_t vtBase  = ((size_t)bh * HDIM) * SEQ + gch * 8;

  // stage one full K|Im|Vt set for k-tile `ktile` into buffer `buf` (6 cp16 per wave)
  auto STAGE_SET = [&](int ktile, short* buf) {
    #pragma unroll
    for (int s = 0; s < 6; ++s) {
      const int I = w * 6 + s;
      const int tz = I >> 3;
      const int row = ((I & 7) * 8) + lrow8;
      const short* g;
      if (tz == 0)      g = Kp  + kimBase + (size_t)(ktile * 64 + row) * EMB;
      else if (tz == 1) g = Imb + kimBase + (size_t)(ktile * 64 + row) * EMB;
      else              g = VtG + vtBase + (size_t)row * SEQ + ktile * 64;
      cp16(g, &buf[I * 512]);
    }
  };

  const int swz = c31 & 7;         // row-XOR (same for rows c31 and 32+c31)

  // one full compute phase on the committed set `cur` (QK -> exp -> pack -> PV)
  auto PHASE = [&](const short* cur) {
    f32x16 s0 = {}, s1 = {};
    __builtin_amdgcn_s_setprio(1);
    #pragma unroll
    for (int ks = 0; ks < 4; ++ks) {
      const int ch = ((ks * 2 + hi) ^ swz) * 8;
      const int r0off = c31 * 64 + ch, r1off = (32 + c31) * 64 + ch;
      short8 k0 = *(const short8*)&cur[r0off];
      short8 k1 = *(const short8*)&cur[r1off];
      short8 i0 = *(const short8*)&cur[4096 + r0off];
      short8 i1 = *(const short8*)&cur[4096 + r1off];
      s0 = __builtin_amdgcn_mfma_f32_32x32x16_bf16(k0, bq_[ks], s0, 0, 0, 0);
      s1 = __builtin_amdgcn_mfma_f32_32x32x16_bf16(k1, bq_[ks], s1, 0, 0, 0);
      s0 = __builtin_amdgcn_mfma_f32_32x32x16_bf16(i0, bim[ks], s0, 0, 0, 0);
      s1 = __builtin_amdgcn_mfma_f32_32x32x16_bf16(i1, bim[ks], s1, 0, 0, 0);
    }
    __builtin_amdgcn_s_setprio(0);

    // exp, fully in-register. Lane L holds P[q=c31][k = (reg&3)+8*(reg>>2)+4*hi (+32 for s1)]
    float p0[16], p1[16];
    #pragma unroll
    for (int r = 0; r < 16; ++r) {
      p0[r] = __builtin_amdgcn_exp2f(s0[r] * SC);
      p1[r] = __builtin_amdgcn_exp2f(s1[r] * SC);
      lrA += p0[r];
      lrB += p1[r];
    }

    // pack P -> PV A-frags via cvt_pk + permlane32_swap.
    short8 ap[4];
    #pragma unroll
    for (int half = 0; half < 2; ++half) {
      {
        u32x2 sA = __builtin_amdgcn_permlane32_swap(
            cvt_pk_bf16(p0[half*8+0], p0[half*8+1]), cvt_pk_bf16(p0[half*8+4], p0[half*8+5]), false, false);
        u32x2 sB = __builtin_amdgcn_permlane32_swap(
            cvt_pk_bf16(p0[half*8+2], p0[half*8+3]), cvt_pk_bf16(p0[half*8+6], p0[half*8+7]), false, false);
        u32x4 wv = {sA[0], sB[0], sA[1], sB[1]};
        ap[half] = __builtin_bit_cast(short8, wv);
      }
      {
        u32x2 sA = __builtin_amdgcn_permlane32_swap(
            cvt_pk_bf16(p1[half*8+0], p1[half*8+1]), cvt_pk_bf16(p1[half*8+4], p1[half*8+5]), false, false);
        u32x2 sB = __builtin_amdgcn_permlane32_swap(
            cvt_pk_bf16(p1[half*8+2], p1[half*8+3]), cvt_pk_bf16(p1[half*8+6], p1[half*8+7]), false, false);
        u32x4 wv = {sA[0], sB[0], sA[1], sB[1]};
        ap[2 + half] = __builtin_bit_cast(short8, wv);
      }
    }

    // PV phase: A = P frags, B = Vt rows (d = db*32 + c31). out col = d, row = q.
    __builtin_amdgcn_s_setprio(1);
    #pragma unroll
    for (int ks = 0; ks < 4; ++ks) {
      const int ch = ((ks * 2 + hi) ^ swz) * 8;
      short8 v0 = *(const short8*)&cur[8192 + c31 * 64 + ch];
      short8 v1 = *(const short8*)&cur[8192 + (32 + c31) * 64 + ch];
      o0 = __builtin_amdgcn_mfma_f32_32x32x16_bf16(ap[ks], v0, o0, 0, 0, 0);
      o1 = __builtin_amdgcn_mfma_f32_32x32x16_bf16(ap[ks], v1, o1, 0, 0, 0);
    }
    __builtin_amdgcn_s_setprio(0);
  };

  // prologue: stage sets for kt=0 (buf0) then kt=1 (buf1) — issue order matters for WAITV
  STAGE_SET(0, tiles[0]);
  STAGE_SET(1, tiles[1]);

  #pragma unroll 1
  for (int kt = 0; kt < 15; ++kt) {
    WAITV(6); BARRIER();               // own set(kt) loads done -> all waves' set(kt) committed
    const short* cur = tiles[kt & 1];
    PHASE(cur);
    BARRIER();                         // all waves done reading set(kt)
    if (kt <= 13)
      STAGE_SET(kt + 2, tiles[kt & 1]);   // overwrite the buffer just freed
  }
  WAITV(0); BARRIER();                 // final set (kt=15) committed
  PHASE(tiles[1]);

  // epilogue: lane pair (L, L+32) hold disjoint k-halves of q=c31's denominator
  float lr = lrA + lrB;
  lr += __shfl_xor(lr, 32);
  float inv = 1.f / lr;                  // valid for q-row (qb + w*32 + c31), all lanes

  // o[db][r] = O[q = qb+w*32+(r&3)+8*(r>>2)+4*hi][d = db*32 + c31]
  #pragma unroll
  for (int r = 0; r < 16; ++r) {
    const int qr = (r & 3) + 8 * (r >> 2) + 4 * hi;
    const float invr = __shfl(inv, qr);  // lane qr holds inv for q-row qb+w*32+qr
    const size_t base = ((size_t)(b * SEQ + qb + w * 32 + qr)) * EMB + h * HDIM + c31;
    attnA[base]      = (short)f2bf_fast(o0[r] * invr);
    attnA[base + 32] = (short)f2bf_fast(o1[r] * invr);
  }
}

// ---------------------------------------------------------------- launch
extern "C" void kernel_launch(void* const* d_in, const int* in_sizes, int n_in,
                              void* d_out, int out_size, void* d_ws, size_t ws_size,
                              hipStream_t stream) {
  const float* Re  = (const float*)d_in[0];
  const float* Im  = (const float*)d_in[1];
  const float* pos = (const float*)d_in[2];
  const float* Wq  = (const float*)d_in[3];
  const float* bq  = (const float*)d_in[4];
  const float* Wk  = (const float*)d_in[5];
  const float* bk  = (const float*)d_in[6];
  const float* Wv  = (const float*)d_in[7];
  const float* bv  = (const float*)d_in[8];
  const float* Wo  = (const float*)d_in[9];
  const float* bo  = (const float*)d_in[10];

  short* ws    = (short*)d_ws;
  short* Rebf  = ws;                         // 4M shorts
  short* Imbf  = ws + (size_t)MELEM;         // 4M
  short* Wt    = ws + (size_t)2 * MELEM;     // 4 x 1M (q,k,v,o)
  short* Qp    = ws + (size_t)3 * MELEM;     // Q,K projections + Vt: 3 x 4M
  short* Kp    = Qp + (size_t)MELEM;
  short* VtG   = Qp + (size_t)2 * MELEM;     // V transposed [b,h,d,s]
  short* attnA = ws + (size_t)6 * MELEM;     // 4M

  // fused convert + weight transpose (one launch)
  prep<<<dim3(12288), 256, 0, stream>>>(Re, Im, Rebf, Imbf, Wq, Wk, Wv, Wo, Wt);

  // fused Q/K/V projection (+bias +P), bf16 out; V written transposed. N fused to 3072.
  gemm_qkv<<<dim3(3 * EMB / 128, MTOT / 128), 256, 0, stream>>>(
      Rebf, Wt, bq, bk, bv, pos, Qp, VtG);

  // flash attention (x = bh for XCD-local L2 reuse of K/Im/Vt), 128-row q-tiles
  attn<<<dim3(BATCH * NHEAD, SEQ / 128), 256, 0, stream>>>(
      Qp, Kp, VtG, Imbf, attnA);

  // output projection, f32 out, 64x64 tiles, true pipeline
  gemm_wo<<<dim3(EMB / 64, MTOT / 64), 256, 0, stream>>>(
      attnA, Wt + 3 * EMB * EMB, bo, (float*)d_out);
}

// Round 8
// 192.072 us; speedup vs baseline: 1.0171x; 1.0171x over previous
//
#include <hip/hip_runtime.h>
#include <hip/hip_bf16.h>
#include <stdint.h>

// Problem constants
#define BATCH 4
#define SEQ   1024
#define EMB   1024
#define NHEAD 16
#define HDIM  64
#define MTOT  (BATCH*SEQ)          // 4096 rows
#define MELEM (MTOT*EMB)           // 4,194,304 elements per [B,S,E] tensor

typedef __attribute__((ext_vector_type(8))) short short8;
typedef __attribute__((ext_vector_type(4))) float f32x4;
typedef __attribute__((ext_vector_type(16))) float f32x16;
typedef __attribute__((ext_vector_type(4))) unsigned short us4;
typedef __attribute__((ext_vector_type(2))) unsigned int u32x2;
typedef __attribute__((ext_vector_type(4))) unsigned int u32x4;

// counted vmem wait (T4): NEVER drain to 0 inside a pipelined loop.
#define WAITV(N) asm volatile("s_waitcnt vmcnt(" #N ")" ::: "memory")
#define BARRIER() __builtin_amdgcn_s_barrier()

// fast f32->bf16: round-half-up via integer add (inputs finite, no NaN).
static __device__ __forceinline__ unsigned short f2bf_fast(float f) {
  unsigned u = __builtin_bit_cast(unsigned, f);
  return (unsigned short)((u + 0x8000u) >> 16);
}

// packed f32x2 -> bf16x2 (RNE), no builtin on gfx950 (T12/m240) -> inline asm
static __device__ __forceinline__ unsigned cvt_pk_bf16(float lo, float hi) {
  unsigned r;
  asm("v_cvt_pk_bf16_f32 %0, %1, %2" : "=v"(r) : "v"(lo), "v"(hi));
  return r;
}

// async global->LDS, 16B per lane. lds ptr must be WAVE-UNIFORM base;
// HW scatters lane i to base + i*16. (m97 recipe)
static __device__ __forceinline__ void cp16(const void* g, const void* lds_uniform) {
  __builtin_amdgcn_global_load_lds(
      (const __attribute__((address_space(1))) unsigned int*)(uintptr_t)g,
      (__attribute__((address_space(3))) unsigned int*)(unsigned int)(uintptr_t)lds_uniform,
      16, 0, 0);
}

// ---------------------------------------------------------------- prep: cvt f32->bf16 (Re,Im) + W transpose x4
// bid 0..4095: Re cvt | 4096..8191: Im cvt | 8192..12287: wtrans (z = (bid-8192)>>10)
__global__ __launch_bounds__(256) void prep(const float* __restrict__ Re,
                                            const float* __restrict__ Im,
                                            short* __restrict__ Rebf,
                                            short* __restrict__ Imbf,
                                            const float* __restrict__ W0,
                                            const float* __restrict__ W1,
                                            const float* __restrict__ W2,
                                            const float* __restrict__ W3,
                                            short* __restrict__ WtBase) {
  __shared__ short tile[32][33];
  const int bid = blockIdx.x;
  if (bid < 8192) {
    const float* in  = (bid >= 4096) ? Im   : Re;
    short*       out = (bid >= 4096) ? Imbf : Rebf;
    int i = (bid & 4095) * 256 + threadIdx.x;   // each thread: 4 elements
    float4 f = ((const float4*)in)[i];
    unsigned r0 = ((unsigned)f2bf_fast(f.y) << 16) | f2bf_fast(f.x);
    unsigned r1 = ((unsigned)f2bf_fast(f.w) << 16) | f2bf_fast(f.z);
    ((uint2*)out)[i] = make_uint2(r0, r1);
  } else {
    const int wb = bid - 8192;
    const int z = wb >> 10;
    const float* W = (z == 0) ? W0 : (z == 1) ? W1 : (z == 2) ? W2 : W3;
    short* Wt = WtBase + (size_t)z * EMB * EMB;
    const int rem = wb & 1023;
    const int nT = (rem & 31) * 32, kT = (rem >> 5) * 32;
    const int tx = threadIdx.x & 31, ty = threadIdx.x >> 5;   // 32 x 8
    #pragma unroll
    for (int i = 0; i < 4; ++i)
      tile[ty + 8*i][tx] = (short)f2bf_fast(W[(size_t)(kT + ty + 8*i) * EMB + nT + tx]);
    __syncthreads();
    #pragma unroll
    for (int i = 0; i < 4; ++i)
      Wt[(size_t)(nT + ty + 8*i) * EMB + kT + tx] = tile[tx][ty + 8*i];
  }
}

// ---------------------------------------------------------------- fused QKV GEMM, 128x128 tiles + T4 pipeline
// N fused to 3072. grid (24,32) = 768 blocks, 64 KB LDS -> 2 blocks/CU. (control — parked at ~41 us;
// three structurally different variants all land 40-42.5: short-K regime is the invariant.)
__global__ __launch_bounds__(256) void gemm_qkv(const short* __restrict__ A,
                                                const short* __restrict__ Wt,
                                                const float* __restrict__ bq,
                                                const float* __restrict__ bk,
                                                const float* __restrict__ bv,
                                                const float* __restrict__ pos,
                                                short* __restrict__ QKbase,
                                                short* __restrict__ vtOut) {
  const int m0 = blockIdx.y * 128, n0 = blockIdx.x * 128;
  const int z = n0 >> 10;                       // 0=Q 1=K 2=V (1024 % 128 == 0)
  const float* bias = (z == 0) ? bq : (z == 1 ? bk : bv);

  __shared__ __align__(16) short As[2][128 * 64];  // 2 x 16 KB
  __shared__ __align__(16) short Bs[2][128 * 64];  // 2 x 16 KB

  const int t = threadIdx.x;
  const int lane = t & 63, w = t >> 6;
  const int wm = w >> 1, wn = w & 1;            // wave tile 64m x 64n
  const int quad = lane >> 4, l16 = lane & 15;
  const int lrow8 = lane >> 3, lchunk = lane & 7;
  const int gch = lchunk ^ lrow8;               // swizzled source chunk
  const int sw7 = l16 & 7;

  const short* Arow = A  + (size_t)(m0 + w * 32 + lrow8) * EMB + gch * 8;
  const short* Brow = Wt + (size_t)(n0 + w * 32 + lrow8) * EMB + gch * 8;

  f32x4 acc[4][4] = {};

  auto STAGE = [&](short* as, short* bs, int k0) {   // 8 cp16 per thread
    #pragma unroll
    for (int s = 0; s < 4; ++s)
      cp16(Arow + (size_t)(s * 8) * EMB + k0, &as[(w * 32 + s * 8) * 64]);
    #pragma unroll
    for (int s = 0; s < 4; ++s)
      cp16(Brow + (size_t)(s * 8) * EMB + k0, &bs[(w * 32 + s * 8) * 64]);
  };
  auto COMPUTE = [&](const short* as, const short* bs) {
    #pragma unroll
    for (int ks = 0; ks < 2; ++ks) {
      const int chv = ((ks << 2) + quad) ^ sw7;
      short8 af[4], bfr[4];
      #pragma unroll
      for (int i = 0; i < 4; ++i)
        af[i] = *(const short8*)&as[(wm * 64 + i * 16 + l16) * 64 + chv * 8];
      #pragma unroll
      for (int j = 0; j < 4; ++j)
        bfr[j] = *(const short8*)&bs[(wn * 64 + j * 16 + l16) * 64 + chv * 8];
      #pragma unroll
      for (int i = 0; i < 4; ++i)
        #pragma unroll
        for (int j = 0; j < 4; ++j)
          acc[i][j] = __builtin_amdgcn_mfma_f32_16x16x32_bf16(af[i], bfr[j], acc[i][j], 0, 0, 0);
    }
  };

  STAGE(As[0], Bs[0], 0);      // tile 0 in flight
  STAGE(As[1], Bs[1], 64);     // tile 1 in flight (16 loads outstanding)

  #pragma unroll 1
  for (int p = 0; p < 7; ++p) {
    WAITV(8); BARRIER();                    // own tile-(2p) loads done; all waves synced
    COMPUTE(As[0], Bs[0]);                  // k = p*128
    BARRIER();                              // all waves done reading buf0
    STAGE(As[0], Bs[0], p * 128 + 128);     // tile 2p+2
    WAITV(8); BARRIER();
    COMPUTE(As[1], Bs[1]);                  // k = p*128 + 64
    BARRIER();
    STAGE(As[1], Bs[1], p * 128 + 192);     // tile 2p+3
  }
  WAITV(8); BARRIER();
  COMPUTE(As[0], Bs[0]);                    // k = 896
  BARRIER();
  WAITV(0); BARRIER();
  COMPUTE(As[1], Bs[1]);                    // k = 960

  // epilogue: C row = quad*4+r, col = l16
  #pragma unroll
  for (int i = 0; i < 4; ++i) {
    int mbase = m0 + wm * 64 + i * 16 + quad * 4;
    #pragma unroll
    for (int j = 0; j < 4; ++j) {
      int n = n0 + wn * 64 + j * 16 + l16;
      int nl = n & 1023;
      float bn = bias[nl];
      int d = nl & (HDIM - 1);
      if (z == 2) {
        // write V transposed: [b,h,d,s] so attn stages Vt rows contiguously
        int bh = (mbase >> 10) * NHEAD + (nl >> 6);
        int s = mbase & (SEQ - 1);
        us4 pk;
        #pragma unroll
        for (int r = 0; r < 4; ++r) {
          float v = acc[i][j][r] + bn + pos[(size_t)(mbase + r) * HDIM + d];
          pk[r] = f2bf_fast(v);
        }
        *(us4*)&vtOut[((size_t)bh * HDIM + d) * SEQ + s] = pk;
      } else {
        #pragma unroll
        for (int r = 0; r < 4; ++r) {
          int mm = mbase + r;
          float v = acc[i][j][r] + bn + pos[(size_t)mm * HDIM + d];
          QKbase[(size_t)z * MELEM + (size_t)mm * EMB + nl] = (short)f2bf_fast(v);
        }
      }
    }
  }
}

// ---------------------------------------------------------------- Wo GEMM: 64x64 tiles, true pipeline (control)
__global__ __launch_bounds__(256) void gemm_wo(const short* __restrict__ A,
                                               const short* __restrict__ Bt,
                                               const float* __restrict__ bias,
                                               float* __restrict__ out) {
  const int m0 = blockIdx.y * 64, n0 = blockIdx.x * 64;

  __shared__ __align__(16) short As[2][64 * 64];
  __shared__ __align__(16) short Bs[2][64 * 64];

  const int t = threadIdx.x;
  const int lane = t & 63, w = t >> 6;
  const int wm = w >> 1, wn = w & 1;          // wave tile: 32m x 32n
  const int quad = lane >> 4, l16 = lane & 15;
  const int lrow8 = lane >> 3, lchunk = lane & 7;
  const int gch = lchunk ^ lrow8;
  const int sw7 = l16 & 7;

  const short* Arow = A  + (size_t)(m0 + w * 16 + lrow8) * EMB + gch * 8;
  const short* Brow = Bt + (size_t)(n0 + w * 16 + lrow8) * EMB + gch * 8;

  f32x4 acc[2][2] = {};

  auto STAGE = [&](short* as, short* bs, int k0) {   // 4 cp16 per thread
    #pragma unroll
    for (int s = 0; s < 2; ++s) {
      cp16(Arow + (size_t)(s * 8) * EMB + k0, &as[(w * 16 + s * 8) * 64]);
      cp16(Brow + (size_t)(s * 8) * EMB + k0, &bs[(w * 16 + s * 8) * 64]);
    }
  };
  auto COMPUTE = [&](const short* as, const short* bs) {
    #pragma unroll
    for (int ks = 0; ks < 2; ++ks) {
      const int chv = ((ks << 2) + quad) ^ sw7;
      short8 af[2], bfr[2];
      #pragma unroll
      for (int i = 0; i < 2; ++i)
        af[i] = *(const short8*)&as[(wm * 32 + i * 16 + l16) * 64 + chv * 8];
      #pragma unroll
      for (int j = 0; j < 2; ++j)
        bfr[j] = *(const short8*)&bs[(wn * 32 + j * 16 + l16) * 64 + chv * 8];
      #pragma unroll
      for (int i = 0; i < 2; ++i)
        #pragma unroll
        for (int j = 0; j < 2; ++j)
          acc[i][j] = __builtin_amdgcn_mfma_f32_16x16x32_bf16(af[i], bfr[j], acc[i][j], 0, 0, 0);
    }
  };

  STAGE(As[0], Bs[0], 0);
  STAGE(As[1], Bs[1], 64);

  #pragma unroll 1
  for (int p = 0; p < 7; ++p) {
    WAITV(4); BARRIER();
    COMPUTE(As[0], Bs[0]);
    BARRIER();
    STAGE(As[0], Bs[0], p * 128 + 128);
    WAITV(4); BARRIER();
    COMPUTE(As[1], Bs[1]);
    BARRIER();
    STAGE(As[1], Bs[1], p * 128 + 192);
  }
  WAITV(4); BARRIER();
  COMPUTE(As[0], Bs[0]);
  BARRIER();
  WAITV(0); BARRIER();
  COMPUTE(As[1], Bs[1]);

  #pragma unroll
  for (int i = 0; i < 2; ++i) {
    int mbase = m0 + wm * 32 + i * 16 + quad * 4;
    #pragma unroll
    for (int j = 0; j < 2; ++j) {
      int n = n0 + wn * 32 + j * 16 + l16;
      float bn = bias[n];
      #pragma unroll
      for (int r = 0; r < 4; ++r)
        out[(size_t)(mbase + r) * EMB + n] = acc[i][j][r] + bn;
    }
  }
}

// ---------------------------------------------------------------- flash attention v5: R6/v3 structure
// (single-buffered, __syncthreads-committed, proven 190.2-us config) with ONE change:
// 4-bit-spread LDS swizzle. v3's swz = row&7 put the 4 lanes {x, x+8, x+16, x+24}
// (equal c31&7) on the SAME 16B bank group -> measured 4-way conflict (3.1M cycles/dispatch
// = 4 cyc per ds_read_b128, R7 counters). New: swz(row) = (row ^ (row>>3)) & 7 —
// those 4 lanes now get slots x^0,x^1,x^2,x^3 (distinct), and lanes 0..7 still cover
// all 8 slots. Staging matches (rule #21, both-sides-or-neither): global pre-swizzle
// gch = lchunk ^ lrow8 ^ (I&7), since row = (I&7)*8 + lrow8 -> row&7 = lrow8, row>>3 = I&7.
__global__ __launch_bounds__(256) void attn(const short* __restrict__ Qp,
                                            const short* __restrict__ Kp,
                                            const short* __restrict__ VtG,
                                            const short* __restrict__ Imb,
                                            short* __restrict__ attnA) {
  const int qb = blockIdx.y * 128;
  const int bh = blockIdx.x;
  const int b = bh >> 4, h = bh & 15;
  const int t = threadIdx.x, lane = t & 63, w = t >> 6;   // w: 0..3
  const int c31 = lane & 31;       // q-row (QK out col / PV A row) and d-row (PV out col)
  const int hi  = lane >> 5;       // half-wave: k-slice selector
  const int lrow8 = lane >> 3, lchunk = lane & 7;

  __shared__ __align__(16) short tiles[3 * 64 * 64];   // K | Im | Vt  (24576 B)

  // Q/Im B-fragments in regs: lane holds row (qb + w*32 + c31), k = ks*16 + hi*8 .. +8
  const int qrow = qb + w * 32 + c31;
  const size_t qbase = ((size_t)(b * SEQ + qrow)) * EMB + h * HDIM + hi * 8;
  short8 bq_[4], bim[4];
  #pragma unroll
  for (int ks = 0; ks < 4; ++ks) {
    bq_[ks] = *(const short8*)&Qp [qbase + ks * 16];
    bim[ks] = *(const short8*)&Imb[qbase + ks * 16];
  }

  float lrA = 0.f, lrB = 0.f;      // per-lane softmax denominator (q = qrow), split chains
  f32x16 o0 = {}, o1 = {};         // PV accum, d-blocks 0/1

  const float SC = 0.03125f * 1.44269504089f;   // /sqrt(1024) * log2(e)
  const size_t kimBase = ((size_t)b * SEQ) * EMB + h * HDIM;   // no gch here (per-I swizzle)
  const size_t vtBase  = ((size_t)bh * HDIM) * SEQ;

  // prologue: stage all of tile 0 (6 cp16 per wave = 24 total = 3 x 8 KB)
  #pragma unroll
  for (int s = 0; s < 6; ++s) {
    const int I = w * 6 + s;
    const int tz = I >> 3;
    const int row = ((I & 7) * 8) + lrow8;
    const int gch = lchunk ^ lrow8 ^ (I & 7);    // 4-bit-spread staging swizzle
    const short* g;
    if (tz == 0)      g = Kp  + kimBase + (size_t)row * EMB + gch * 8;
    else if (tz == 1) g = Imb + kimBase + (size_t)row * EMB + gch * 8;
    else              g = VtG + vtBase + (size_t)row * SEQ + gch * 8;
    cp16(g, &tiles[I * 512]);
  }
  __syncthreads();

  // read-side swizzles: row c31 -> swzA; row 32+c31 -> swzB = swzA ^ 4
  const int swzA = (c31 ^ (c31 >> 3)) & 7;
  const int swzB = swzA ^ 4;

  for (int kt = 0; kt < 16; ++kt) {
    const int kBaseN = (kt + 1) * 64;   // next tile base (unused when kt==15)

    // ---- QK phase (swapped): out row = k, col = q. A = K/Im rows from LDS, B = Q/Im regs.
    f32x16 s0 = {}, s1 = {};
    #pragma unroll
    for (int ks = 0; ks < 4; ++ks) {
      const int ch0 = ((ks * 2 + hi) ^ swzA) * 8;
      const int ch1 = ((ks * 2 + hi) ^ swzB) * 8;
      const int r0off = c31 * 64 + ch0, r1off = (32 + c31) * 64 + ch1;
      short8 k0 = *(const short8*)&tiles[r0off];
      short8 k1 = *(const short8*)&tiles[r1off];
      short8 i0 = *(const short8*)&tiles[4096 + r0off];
      short8 i1 = *(const short8*)&tiles[4096 + r1off];
      s0 = __builtin_amdgcn_mfma_f32_32x32x16_bf16(k0, bq_[ks], s0, 0, 0, 0);
      s1 = __builtin_amdgcn_mfma_f32_32x32x16_bf16(k1, bq_[ks], s1, 0, 0, 0);
      s0 = __builtin_amdgcn_mfma_f32_32x32x16_bf16(i0, bim[ks], s0, 0, 0, 0);
      s1 = __builtin_amdgcn_mfma_f32_32x32x16_bf16(i1, bim[ks], s1, 0, 0, 0);
    }

    __syncthreads();   // BAR_A: all waves done reading K/Im(kt); Vt(kt) committed

    // ---- stage K/Im for kt+1 (4 cp16 per wave = 16 KB); commits at BAR_B
    if (kt != 15) {
      #pragma unroll
      for (int s = 0; s < 4; ++s) {
        const int I = w * 4 + s;            // 0..15
        const int row = ((I & 7) * 8) + lrow8;
        const int gch = lchunk ^ lrow8 ^ (I & 7);
        const short* g = ((I >> 3) ? Imb : Kp) + kimBase + (size_t)(kBaseN + row) * EMB + gch * 8;
        cp16(g, &tiles[I * 512]);
      }
    }

    // ---- exp, fully in-register. Lane L holds P[q=c31][k = (reg&3)+8*(reg>>2)+4*hi (+32 for s1)]
    float p0[16], p1[16];
    #pragma unroll
    for (int r = 0; r < 16; ++r) {
      p0[r] = __builtin_amdgcn_exp2f(s0[r] * SC);
      p1[r] = __builtin_amdgcn_exp2f(s1[r] * SC);
      lrA += p0[r];
      lrB += p1[r];
    }

    // ---- pack P -> PV A-frags via cvt_pk + permlane32_swap.
    // frag[ks] elems e: k = ks*16 + hi*8 + e. Pairs (p0,p1)&(p4,p5) -> words 0,2; (p2,p3)&(p6,p7) -> 1,3.
    short8 ap[4];
    #pragma unroll
    for (int half = 0; half < 2; ++half) {        // regs 0..7 / 8..15 -> ks = 2*kb + half
      {
        u32x2 sA = __builtin_amdgcn_permlane32_swap(
            cvt_pk_bf16(p0[half*8+0], p0[half*8+1]), cvt_pk_bf16(p0[half*8+4], p0[half*8+5]), false, false);
        u32x2 sB = __builtin_amdgcn_permlane32_swap(
            cvt_pk_bf16(p0[half*8+2], p0[half*8+3]), cvt_pk_bf16(p0[half*8+6], p0[half*8+7]), false, false);
        u32x4 wv = {sA[0], sB[0], sA[1], sB[1]};
        ap[half] = __builtin_bit_cast(short8, wv);
      }
      {
        u32x2 sA = __builtin_amdgcn_permlane32_swap(
            cvt_pk_bf16(p1[half*8+0], p1[half*8+1]), cvt_pk_bf16(p1[half*8+4], p1[half*8+5]), false, false);
        u32x2 sB = __builtin_amdgcn_permlane32_swap(
            cvt_pk_bf16(p1[half*8+2], p1[half*8+3]), cvt_pk_bf16(p1[half*8+6], p1[half*8+7]), false, false);
        u32x4 wv = {sA[0], sB[0], sA[1], sB[1]};
        ap[2 + half] = __builtin_bit_cast(short8, wv);
      }
    }

    // ---- PV phase: A = P frags, B = Vt rows (d = db*32 + c31) from LDS. out col = d, row = q.
    #pragma unroll
    for (int ks = 0; ks < 4; ++ks) {
      const int ch0 = ((ks * 2 + hi) ^ swzA) * 8;
      const int ch1 = ((ks * 2 + hi) ^ swzB) * 8;
      short8 v0 = *(const short8*)&tiles[8192 + c31 * 64 + ch0];
      short8 v1 = *(const short8*)&tiles[8192 + (32 + c31) * 64 + ch1];
      o0 = __builtin_amdgcn_mfma_f32_32x32x16_bf16(ap[ks], v0, o0, 0, 0, 0);
      o1 = __builtin_amdgcn_mfma_f32_32x32x16_bf16(ap[ks], v1, o1, 0, 0, 0);
    }

    __syncthreads();   // BAR_B: all waves done reading Vt(kt); K/Im(kt+1) committed

    // ---- stage Vt for kt+1 (2 cp16 per wave = 8 KB); commits at next BAR_A
    if (kt != 15) {
      #pragma unroll
      for (int s = 0; s < 2; ++s) {
        const int I = 16 + w * 2 + s;       // 16..23
        const int row = ((I & 7) * 8) + lrow8;
        const int gch = lchunk ^ lrow8 ^ (I & 7);
        cp16(VtG + vtBase + (size_t)row * SEQ + kBaseN + gch * 8, &tiles[I * 512]);
      }
    }
  }

  // epilogue: lane pair (L, L+32) hold disjoint k-halves of q=c31's denominator
  float lr = lrA + lrB;
  lr += __shfl_xor(lr, 32);
  float inv = 1.f / lr;                  // valid for q-row (qb + w*32 + c31), all lanes

  // o[db][r] = O[q = qb+w*32+(r&3)+8*(r>>2)+4*hi][d = db*32 + c31]
  #pragma unroll
  for (int r = 0; r < 16; ++r) {
    const int qr = (r & 3) + 8 * (r >> 2) + 4 * hi;
    const float invr = __shfl(inv, qr);  // lane qr holds inv for q-row qb+w*32+qr
    const size_t base = ((size_t)(b * SEQ + qb + w * 32 + qr)) * EMB + h * HDIM + c31;
    attnA[base]      = (short)f2bf_fast(o0[r] * invr);
    attnA[base + 32] = (short)f2bf_fast(o1[r] * invr);
  }
}

// ---------------------------------------------------------------- launch
extern "C" void kernel_launch(void* const* d_in, const int* in_sizes, int n_in,
                              void* d_out, int out_size, void* d_ws, size_t ws_size,
                              hipStream_t stream) {
  const float* Re  = (const float*)d_in[0];
  const float* Im  = (const float*)d_in[1];
  const float* pos = (const float*)d_in[2];
  const float* Wq  = (const float*)d_in[3];
  const float* bq  = (const float*)d_in[4];
  const float* Wk  = (const float*)d_in[5];
  const float* bk  = (const float*)d_in[6];
  const float* Wv  = (const float*)d_in[7];
  const float* bv  = (const float*)d_in[8];
  const float* Wo  = (const float*)d_in[9];
  const float* bo  = (const float*)d_in[10];

  short* ws    = (short*)d_ws;
  short* Rebf  = ws;                         // 4M shorts
  short* Imbf  = ws + (size_t)MELEM;         // 4M
  short* Wt    = ws + (size_t)2 * MELEM;     // 4 x 1M (q,k,v,o)
  short* Qp    = ws + (size_t)3 * MELEM;     // Q,K projections + Vt: 3 x 4M
  short* Kp    = Qp + (size_t)MELEM;
  short* VtG   = Qp + (size_t)2 * MELEM;     // V transposed [b,h,d,s]
  short* attnA = ws + (size_t)6 * MELEM;     // 4M

  // fused convert + weight transpose (one launch)
  prep<<<dim3(12288), 256, 0, stream>>>(Re, Im, Rebf, Imbf, Wq, Wk, Wv, Wo, Wt);

  // fused Q/K/V projection (+bias +P), bf16 out; V written transposed. N fused to 3072.
  gemm_qkv<<<dim3(3 * EMB / 128, MTOT / 128), 256, 0, stream>>>(
      Rebf, Wt, bq, bk, bv, pos, Qp, VtG);

  // flash attention (x = bh for XCD-local L2 reuse of K/Im/Vt), 128-row q-tiles
  attn<<<dim3(BATCH * NHEAD, SEQ / 128), 256, 0, stream>>>(
      Qp, Kp, VtG, Imbf, attnA);

  // output projection, f32 out, 64x64 tiles, true pipeline
  gemm_wo<<<dim3(EMB / 64, MTOT / 64), 256, 0, stream>>>(
      attnA, Wt + 3 * EMB * EMB, bo, (float*)d_out);
}